// Round 11
// baseline (665.251 us; speedup 1.0000x reference)
//
#include <hip/hip_runtime.h>

#define NN 128
#define ME 32
#define DI 64
#define NZ 96
#define ROWD 130
#define MAXIT 5000

// ---- LDS layout (double offsets). R: [0, 16640). Total 20040 dbl = 160320 B <= 163840.
#define OFF_UN 16640
#define ROWB  (OFF_UN)           // [2][128] sweep row-k buffer (phase 2)
#define COLB  (OFF_UN + 256)     // [2][128] sweep col-k buffer (phase 2)
#define PLO2  (OFF_UN)           // [2][4][64] lo partials (loop)
#define PHI2  (OFF_UN + 512)     // [2][4][32] hi partials (loop)
#define TV0   (OFF_UN + 768)     // [2][64] obj per-lane terms (loop, pipelined)
#define TV1   (OFF_UN + 896)     // [2][16] obj stage-A sums (loop, pipelined)
#define FLG   (OFF_UN + 928)     // [2] convergence flag (loop, double 0/1)
#define YBUF  (OFF_UN)           // [128][12] Y block (stage 2)
#define KBUF  (OFF_UN + 1536)    // [12][96] K cols (stage 2)
#define CPART (OFF_UN + 1024)    // [2][128] (stage 3a)
#define VP    (OFF_UN + 1280)    // [4][128] (stage 3b)
#define BASEV (OFF_UN + 1792)    // [96] (persists through loop)
#define QBV   (OFF_UN + 1888)    // [96] (persists through loop)
#define FPART (OFF_UN + 1024)    // [2][128] (final)
#define RHSV  (OFF_UN + 1280)    // [128] (final)
#define XPART (OFF_UN + 1408)    // [2][128] (final)
#define CB    (OFF_UN + 2688)    // [128] c
#define QBUF  (OFF_UN + 2816)    // [128] q
#define V1    (OFF_UN + 2944)    // [128] Rc
#define V2    (OFF_UN + 3072)    // [128] Rq
#define HB    (OFF_UN + 3200)    // [64]
#define BB    (OFF_UN + 3264)    // [32]
#define CST   (OFF_UN + 3296)    // [8]: 0=u.c 1=q.u
#define ZBF   (OFF_UN + 3304)    // [96] z publish (final; no overlap with FPART)
#define LDS_DBL (OFF_UN + 3400)  // 20040

// f32 SGPR broadcast. CONTRACT: source computed by all lanes of the wave.
__device__ __forceinline__ float rlf(float v, int lane) {
  return __uint_as_float((unsigned)__builtin_amdgcn_readlane((int)__float_as_uint(v), lane));
}

__global__ __launch_bounds__(256, 1) void altdiff_kernel(
    const float* __restrict__ Qg, const float* __restrict__ qg,
    const float* __restrict__ Gg, const float* __restrict__ hg,
    const float* __restrict__ Ag, const float* __restrict__ bg,
    float* __restrict__ out)
{
  extern __shared__ double ldsd[];
  double2* lds2 = (double2*)ldsd;

  const int bidx = blockIdx.x;
  const int tid  = threadIdx.x;
  const int w    = tid >> 6;     // wave 0..3
  const int l    = tid & 63;     // lane
  const int lm   = l & 31;
  const int ia   = tid & 127;    // 128-split index
  const int hh   = tid >> 7;     // 0..1 (wave-uniform)

  const float* Qb = Qg + (size_t)bidx * NN * NN;
  const float* Ab = Ag + (size_t)bidx * ME * NN;
  const float* Gb = Gg + (size_t)bidx * DI * NN;
  const float* qb = qg + (size_t)bidx * NN;
  const float* hb = hg + (size_t)bidx * DI;
  const float* bv = bg + (size_t)bidx * ME;

  // stage h, b, q (f64)
  if (tid < DI) ldsd[HB + tid] = (double)hb[tid];
  else if (tid < DI + ME) ldsd[BB + tid - DI] = (double)bv[tid - DI];
  if (tid >= 128) ldsd[QBUF + tid - 128] = (double)qb[tid - 128];

  const int r = tid >> 4, c = tid & 15;   // 8x8 register tile at rows 8r.., cols 8c..
  double acc[8][8];                       // ALL indices compile-time constant (no scratch)

  // ---------------- Phase 1: M = Q + A^T A + G^T G (f64) -> registers ----------------
  {
    const float4* Q4 = (const float4*)Qb;
#pragma unroll
    for (int rr = 0; rr < 8; ++rr) {
      float4 q0 = Q4[((8*r+rr) << 5) + 2*c];
      float4 q1 = Q4[((8*r+rr) << 5) + 2*c + 1];
      acc[rr][0]=(double)q0.x; acc[rr][1]=(double)q0.y; acc[rr][2]=(double)q0.z; acc[rr][3]=(double)q0.w;
      acc[rr][4]=(double)q1.x; acc[rr][5]=(double)q1.y; acc[rr][6]=(double)q1.z; acc[rr][7]=(double)q1.w;
    }
    const float4* A4 = (const float4*)Ab;
    for (int m = 0; m < ME; ++m) {
      float4 u0 = A4[(m << 5) + 2*r], u1 = A4[(m << 5) + 2*r + 1];
      float4 v0 = A4[(m << 5) + 2*c], v1 = A4[(m << 5) + 2*c + 1];
      double uu[8] = {(double)u0.x,(double)u0.y,(double)u0.z,(double)u0.w,
                      (double)u1.x,(double)u1.y,(double)u1.z,(double)u1.w};
      double vv[8] = {(double)v0.x,(double)v0.y,(double)v0.z,(double)v0.w,
                      (double)v1.x,(double)v1.y,(double)v1.z,(double)v1.w};
#pragma unroll
      for (int rr = 0; rr < 8; ++rr)
#pragma unroll
        for (int cc = 0; cc < 8; ++cc)
          acc[rr][cc] = fma(uu[rr], vv[cc], acc[rr][cc]);
    }
    const float4* G4 = (const float4*)Gb;
    for (int d = 0; d < DI; ++d) {
      float4 u0 = G4[(d << 5) + 2*r], u1 = G4[(d << 5) + 2*r + 1];
      float4 v0 = G4[(d << 5) + 2*c], v1 = G4[(d << 5) + 2*c + 1];
      double uu[8] = {(double)u0.x,(double)u0.y,(double)u0.z,(double)u0.w,
                      (double)u1.x,(double)u1.y,(double)u1.z,(double)u1.w};
      double vv[8] = {(double)v0.x,(double)v0.y,(double)v0.z,(double)v0.w,
                      (double)v1.x,(double)v1.y,(double)v1.z,(double)v1.w};
#pragma unroll
      for (int rr = 0; rr < 8; ++rr)
#pragma unroll
        for (int cc = 0; cc < 8; ++cc)
          acc[rr][cc] = fma(uu[rr], vv[cc], acc[rr][cc]);
    }
  }

  // ---------------- Phase 2: register-tile sweep, 1 barrier/pivot, double-buffered ----------
  {
    if (r == 0) {
#pragma unroll
      for (int cc = 0; cc < 8; ++cc) ldsd[ROWB + 8*c + cc] = acc[0][cc];
    }
    if (c == 0) {
#pragma unroll
      for (int rr = 0; rr < 8; ++rr) ldsd[COLB + 8*r + rr] = acc[rr][0];
    }
    __syncthreads();
    for (int k = 0; k < NN; ++k) {
      const int pb = (k & 1) << 7;
      const int krt = k >> 3, kcl = k & 7;
      double rowk[8], colv[8];
#pragma unroll
      for (int cc = 0; cc < 8; ++cc) rowk[cc] = ldsd[ROWB + pb + 8*c + cc];
#pragma unroll
      for (int rr = 0; rr < 8; ++rr) colv[rr] = ldsd[COLB + pb + 8*r + rr];
      const double dkk  = ldsd[ROWB + pb + k];     // same-address broadcast
      const double rcpd = 1.0 / dkk;               // pivots >= 1 (M >= I)
      double rdv[8];
#pragma unroll
      for (int cc = 0; cc < 8; ++cc) rdv[cc] = rowk[cc] * rcpd;
      const bool pivR = (r == krt), pivC = (c == krt);
#pragma unroll
      for (int rr = 0; rr < 8; ++rr) {
        const double cv = colv[rr] * rcpd;
        const bool pr = pivR && (rr == kcl);
#pragma unroll
        for (int cc = 0; cc < 8; ++cc) {
          double gen = fma(-cv, rowk[cc], acc[rr][cc]);
          acc[rr][cc] = pr ? rdv[cc] : gen;
        }
      }
      if (pivC) {
#pragma unroll
        for (int cc = 0; cc < 8; ++cc) if (cc == kcl) {
#pragma unroll
          for (int rr = 0; rr < 8; ++rr) {
            const bool pr2 = pivR && (rr == kcl);
            acc[rr][cc] = pr2 ? -rcpd : colv[rr] * rcpd;
          }
        }
      }
      if (k < NN - 1) {
        const int pb2 = ((k + 1) & 1) << 7;
        const int krt2 = (k + 1) >> 3, kcl2 = (k + 1) & 7;
        if (r == krt2) {
#pragma unroll
          for (int rr = 0; rr < 8; ++rr) if (rr == kcl2) {
#pragma unroll
            for (int cc = 0; cc < 8; ++cc) ldsd[ROWB + pb2 + 8*c + cc] = acc[rr][cc];
          }
        }
        if (c == krt2) {
#pragma unroll
          for (int cc = 0; cc < 8; ++cc) if (cc == kcl2) {
#pragma unroll
            for (int rr = 0; rr < 8; ++rr) ldsd[COLB + pb2 + 8*r + rr] = acc[rr][cc];
          }
        }
      }
      __syncthreads();
    }
#pragma unroll
    for (int rr = 0; rr < 8; ++rr) {
      double2* dst = (double2*)(ldsd + (8*r+rr)*ROWD + 8*c);
#pragma unroll
      for (int t = 0; t < 4; ++t) dst[t] = make_double2(acc[rr][2*t], acc[rr][2*t+1]);
    }
  }
  __syncthreads();

  // ---------------- Stage 2: K = B (R B^T) in 8 blocks of 12 cols (validated r6) --------
  float Kf[24], Kf2[24];
  for (int blk = 0; blk < 8; ++blk) {
    {
      const float* gp[6];
#pragma unroll
      for (int jj = 0; jj < 6; ++jj) {
        int it = 12*blk + 6*hh + jj;
        gp[jj] = (it < DI) ? (Gb + it*NN) : (Ab + (it - DI)*NN);
      }
      double a2[6] = {0,0,0,0,0,0};
#pragma unroll 4
      for (int t = 0; t < NN; ++t) {
        double rv = ldsd[t*ROWD + ia];
#pragma unroll
        for (int jj = 0; jj < 6; ++jj)
          a2[jj] = fma(rv, (double)gp[jj][t], a2[jj]);
      }
      double2* yst = (double2*)(ldsd + YBUF + ia*12 + 6*hh);
#pragma unroll
      for (int p = 0; p < 3; ++p) yst[p] = make_double2(a2[2*p], a2[2*p+1]);
    }
    __syncthreads();
    {
      const int r2 = (ia < NZ) ? ia : 0;
      const float* brow = (r2 < DI) ? (Gb + r2*NN) : (Ab + (r2 - DI)*NN);
      double a2[6] = {0,0,0,0,0,0};
#pragma unroll 4
      for (int t = 0; t < NN; ++t) {
        double bvv = (double)brow[t];
        const double2* yr = (const double2*)(ldsd + YBUF + t*12 + 6*hh);
        double2 y0 = yr[0], y1 = yr[1], y2 = yr[2];
        a2[0] = fma(bvv, y0.x, a2[0]); a2[1] = fma(bvv, y0.y, a2[1]);
        a2[2] = fma(bvv, y1.x, a2[2]); a2[3] = fma(bvv, y1.y, a2[3]);
        a2[4] = fma(bvv, y2.x, a2[4]); a2[5] = fma(bvv, y2.y, a2[5]);
      }
      if (ia < NZ) {
#pragma unroll
        for (int jj = 0; jj < 6; ++jj) ldsd[KBUF + (6*hh + jj)*NZ + ia] = a2[jj];
      }
    }
    __syncthreads();
    if (w == (blk >> 1)) {          // CONSTANT-index copies (r5 spill fix)
      if ((blk & 1) == 0) {
#pragma unroll
        for (int jj = 0; jj < 12; ++jj) {
          Kf [jj] = (float)ldsd[KBUF + jj*NZ + l];
          Kf2[jj] = (float)ldsd[KBUF + jj*NZ + 64 + lm];
        }
      } else {
#pragma unroll
        for (int jj = 0; jj < 12; ++jj) {
          Kf [12+jj] = (float)ldsd[KBUF + jj*NZ + l];
          Kf2[12+jj] = (float)ldsd[KBUF + jj*NZ + 64 + lm];
        }
      }
    }
    __syncthreads();
  }

  // ---------------- Stage 3a: c = q - G^T h - A^T b ----------------
  {
    double s = 0;
#pragma unroll 8
    for (int jc = 0; jc < 48; ++jc) {
      int j = 48*hh + jc;
      double coef = (j < DI) ? ldsd[HB + j] : ldsd[BB + j - DI];
      const float* src = (j < DI) ? (Gb + j*NN) : (Ab + (j - DI)*NN);
      s = fma(-(double)src[ia], coef, s);
    }
    ldsd[CPART + hh*128 + ia] = s;
  }
  __syncthreads();
  if (tid < NN) ldsd[CB + tid] = ldsd[QBUF + tid] + ldsd[CPART + tid] + ldsd[CPART + 128 + tid];
  __syncthreads();

  // ---------------- Stage 3b: v1 = R c, v2 = R q ----------------
  {
    double a = 0, b2 = 0;
#pragma unroll 4
    for (int tt = 0; tt < 64; ++tt) {
      int t = 64*hh + tt;
      double rv = ldsd[t*ROWD + ia];
      a  = fma(rv, ldsd[CB + t], a);
      b2 = fma(rv, ldsd[QBUF + t], b2);
    }
    ldsd[VP + hh*128 + ia] = a;
    ldsd[VP + 256 + hh*128 + ia] = b2;
  }
  __syncthreads();
  if (tid < NN) {
    ldsd[V1 + tid] = ldsd[VP + tid] + ldsd[VP + 128 + tid];
    ldsd[V2 + tid] = ldsd[VP + 256 + tid] + ldsd[VP + 384 + tid];
  }
  __syncthreads();

  // ---------------- Stage 3c: base = B v1, qB = B v2, scalars ----------------
  {
    const int r2 = (ia < NZ) ? ia : 0;
    const float* brow = (r2 < DI) ? (Gb + r2*NN) : (Ab + (r2 - DI)*NN);
    const int voff = hh ? V2 : V1;
    double s = 0;
#pragma unroll 4
    for (int t = 0; t < NN; ++t) s = fma((double)brow[t], ldsd[voff + t], s);
    if (ia < NZ) ldsd[(hh ? QBV : BASEV) + ia] = s;
  }
  if (w == 0) {
    double pc = ldsd[V1+l]*ldsd[CB+l]   + ldsd[V1+64+l]*ldsd[CB+64+l];
    double pq = ldsd[V1+l]*ldsd[QBUF+l] + ldsd[V1+64+l]*ldsd[QBUF+64+l];
#pragma unroll
    for (int off = 32; off >= 1; off >>= 1) { pc += __shfl_xor(pc, off); pq += __shfl_xor(pq, off); }
    if (l == 0) { ldsd[CST] = pc; ldsd[CST+1] = pq; }
  }
  __syncthreads();

  // ---------------- Loop setup: per-wave pruned state ----------------
  // w0: ylo/nu/zlo + obj pipeline + base seed | w1: ylo/nu/zlo | w2: everything + tv + z-ring
  // w3: yhi/lam/zhi. Break via LDS flag (wave 0 computes, all read).
  const double h_r   = ldsd[HB + l];
  const double b_r   = ldsd[BB + lm];
  const double baseA = ldsd[BASEV + l];
  const double baseB = ldsd[BASEV + 64 + lm];
  const double qvA   = ldsd[QBV + l];
  const double qvB   = ldsd[QBV + 64 + lm];
  const double S_uc  = ldsd[CST], S_qu = ldsd[CST + 1];
  double nu = 0.0, lam = 0.0;
  double zlo = 0.0, zhi = 0.0;
  double zAlo = 0.0, zAhi = 0.0, zBlo = 0.0, zBhi = 0.0, zClo = 0.0, zChi = 0.0;  // wave-2 ring
  double res_prev = 1000.0, res_cur = -100.0;   // wave-0 obj recurrence

  // prologue: partials for body 0 (z = 0 -> seed only), buffer 0; flag init
  {
    double a0 = (w == 0) ? baseA : 0.0;
    double a1 = (w == 0) ? baseB : 0.0;
    ldsd[PLO2 + w*64 + l] = a0;
    if (l < 32) ldsd[PHI2 + w*32 + l] = a1;
    if (tid == 0) { ldsd[FLG] = 0.0; ldsd[FLG + 1] = 0.0; }
  }

  // ---------------- ADMM loop: 1 barrier/body; obj+break pipelined 3 deep, wave-0-only ----
  for (int it = 0; it < MAXIT + 3; ++it) {
    __syncthreads();
    const int p  = (it & 1) << 8;
    const int ph = (it & 1) << 7;
    const int bprev = (it + 1) & 1;       // (it-1)&1
    // flag (stored body it-1, decision for obj_{it-3}) — broadcast b64, oldest load
    double fl = ldsd[FLG + bprev];
    // stage B loads (wave 0, pipeline it-2): wave-uniform broadcast
    double t1v[16];
    if (w == 0) {
      const double2* tp = (const double2*)(ldsd + TV1 + bprev*16);
#pragma unroll
      for (int u = 0; u < 8; ++u) { double2 v = tp[u]; t1v[2*u] = v.x; t1v[2*u+1] = v.y; }
    }
    // stage A loads (wave 0, pipeline it-1)
    double a40 = 0, a41 = 0, a42 = 0, a43 = 0;
    if (w == 0) {
      const double2* t0p = (const double2*)(ldsd + TV0 + bprev*64 + (l & 15)*4);
      double2 v0 = t0p[0], v1 = t0p[1];
      a40 = v0.x; a41 = v0.y; a42 = v1.x; a43 = v1.y;
    }
    // partial reads — pruned per wave
    double ylo = 0.0, yhi = 0.0;
    if (w != 3)
      ylo = (ldsd[PLO2 + p + l]       + ldsd[PLO2 + p + 64 + l])
          + (ldsd[PLO2 + p + 128 + l] + ldsd[PLO2 + p + 192 + l]);
    if (w >= 2)
      yhi = (ldsd[PHI2 + ph + lm]      + ldsd[PHI2 + ph + 32 + lm])
          + (ldsd[PHI2 + ph + 64 + lm] + ldsd[PHI2 + ph + 96 + lm]);
    // uniform deferred break BEFORE ring shift: ring = top(it-2) in zC (= stopping body t*)
    if (it >= 3 && fl != 0.0) break;
    // z ring shift (wave 2 only; zA = z at top of THIS body)
    if (w == 2) { zClo = zBlo; zChi = zBhi; zBlo = zAlo; zBhi = zAhi; zAlo = zlo; zAhi = zhi; }
    if (it < MAXIT) {
      if (w != 3) {                 // nu/zlo update (waves 0,1,2)
        double sk = fmax(0.0, -nu - ylo + h_r);
        nu  = nu + ylo + sk - h_r;
        zlo = nu + sk;
      }
      if (w >= 2) {                 // lam/zhi update (waves 2,3)
        lam = lam + yhi - b_r;
        zhi = lam;
      }
      // f32 matvec for next body (f32 K regs, f32 broadcast; base added in f64 on wave 0)
      const float zflo = (float)zlo;
      const float zfhi = (float)zhi;
      float a0f = 0.f, a0g = 0.f, a1f = 0.f, a1g = 0.f;
      if (w == 0) {
#pragma unroll
        for (int j = 0; j < 24; j += 2) {
          float zj  = rlf(zflo, j);
          float zj1 = rlf(zflo, j + 1);
          a0f = fmaf(Kf[j],   zj,  a0f); a1f = fmaf(Kf2[j],   zj,  a1f);
          a0g = fmaf(Kf[j+1], zj1, a0g); a1g = fmaf(Kf2[j+1], zj1, a1g);
        }
      } else if (w == 1) {
#pragma unroll
        for (int j = 0; j < 24; j += 2) {
          float zj  = rlf(zflo, 24 + j);
          float zj1 = rlf(zflo, 24 + j + 1);
          a0f = fmaf(Kf[j],   zj,  a0f); a1f = fmaf(Kf2[j],   zj,  a1f);
          a0g = fmaf(Kf[j+1], zj1, a0g); a1g = fmaf(Kf2[j+1], zj1, a1g);
        }
      } else if (w == 2) {
#pragma unroll
        for (int j = 0; j < 16; j += 2) {
          float zj  = rlf(zflo, 48 + j);
          float zj1 = rlf(zflo, 48 + j + 1);
          a0f = fmaf(Kf[j],   zj,  a0f); a1f = fmaf(Kf2[j],   zj,  a1f);
          a0g = fmaf(Kf[j+1], zj1, a0g); a1g = fmaf(Kf2[j+1], zj1, a1g);
        }
#pragma unroll
        for (int j = 0; j < 8; j += 2) {
          float zj  = rlf(zfhi, j);
          float zj1 = rlf(zfhi, j + 1);
          a0f = fmaf(Kf[16+j],   zj,  a0f); a1f = fmaf(Kf2[16+j],   zj,  a1f);
          a0g = fmaf(Kf[16+j+1], zj1, a0g); a1g = fmaf(Kf2[16+j+1], zj1, a1g);
        }
      } else {
#pragma unroll
        for (int j = 0; j < 24; j += 2) {
          float zj  = rlf(zfhi, 8 + j);
          float zj1 = rlf(zfhi, 8 + j + 1);
          a0f = fmaf(Kf[j],   zj,  a0f); a1f = fmaf(Kf2[j],   zj,  a1f);
          a0g = fmaf(Kf[j+1], zj1, a0g); a1g = fmaf(Kf2[j+1], zj1, a1g);
        }
      }
      double pa0 = (double)(a0f + a0g);
      double pa1 = (double)(a1f + a1g);
      if (w == 0) { pa0 += baseA; pa1 += baseB; }
      ldsd[PLO2 + (p ^ 256) + w*64 + l] = pa0;
      if (l < 32) ldsd[PHI2 + (ph ^ 128) + w*32 + l] = pa1;
      // tv for pipeline `it` (wave 2 — it holds ylo, yhi, and the ring)
      if (w == 2) {
        double tv = fma(qvA, zAlo, -0.5*(zAlo*(baseA + ylo) + ylo*ylo));
        tv += (l < 32) ? fma(qvB, zAhi, -0.5*(zAhi*(baseB + yhi) + yhi*yhi)) : 0.0;
        ldsd[TV0 + (it & 1)*64 + l] = tv;
      }
    }
    // stage A store (wave 0, pipeline it-1): valid when body it-1 wrote TV0
    if (w == 0 && l < 16 && it >= 1 && it <= MAXIT)
      ldsd[TV1 + (it & 1)*16 + l] = (a40 + a41) + (a42 + a43);
    // stage B (wave 0): obj_{it-2} -> rel -> flag
    if (w == 0 && it >= 2 && it <= MAXIT + 1) {
      double s1 = ((t1v[0] + t1v[1]) + (t1v[2] + t1v[3])) + ((t1v[4] + t1v[5]) + (t1v[6] + t1v[7]));
      double s2 = ((t1v[8] + t1v[9]) + (t1v[10] + t1v[11])) + ((t1v[12] + t1v[13]) + (t1v[14] + t1v[15]));
      double obj = (s1 + s2) - 0.5*S_uc + S_qu;
      res_prev = res_cur; res_cur = obj;
      if (l == 0)
        ldsd[FLG + (it & 1)] = (fabs((res_cur - res_prev) / res_prev) <= 1e-5) ? 1.0 : 0.0;
    }
  }

  // ---------------- Final: publish z (wave 2 ring: zC = top-of-stopping-body) -> LDS ------
  if (w == 2) {
    ldsd[ZBF + l] = zClo;
    if (l < 32) ldsd[ZBF + 64 + l] = zChi;
  }
  __syncthreads();
  // x = R (c + B^T z); z read via broadcast LDS loads
  {
    double s = 0;
#pragma unroll 8
    for (int jc = 0; jc < 48; ++jc) {
      int j = 48*hh + jc;
      double zj = ldsd[ZBF + j];
      const float* src = (j < DI) ? (Gb + j*NN) : (Ab + (j - DI)*NN);
      s = fma((double)src[ia], zj, s);
    }
    ldsd[FPART + hh*128 + ia] = s;
  }
  __syncthreads();
  if (tid < NN) ldsd[RHSV + tid] = ldsd[CB + tid] + ldsd[FPART + tid] + ldsd[FPART + 128 + tid];
  __syncthreads();
  {
    double s = 0;
#pragma unroll 4
    for (int tt = 0; tt < 64; ++tt) {
      int t = 64*hh + tt;
      s = fma(ldsd[t*ROWD + ia], ldsd[RHSV + t], s);   // R[t][ia] = R[ia][t]
    }
    ldsd[XPART + hh*128 + ia] = s;
  }
  __syncthreads();
  if (tid < NN)
    out[(size_t)bidx * NN + tid] = (float)(ldsd[XPART + tid] + ldsd[XPART + 128 + tid]);
}

extern "C" void kernel_launch(void* const* d_in, const int* in_sizes, int n_in,
                              void* d_out, int out_size, void* d_ws, size_t ws_size,
                              hipStream_t stream) {
  (void)in_sizes; (void)n_in; (void)out_size; (void)d_ws; (void)ws_size;
  const float* Q = (const float*)d_in[0];
  const float* q = (const float*)d_in[1];
  const float* G = (const float*)d_in[2];
  const float* h = (const float*)d_in[3];
  const float* A = (const float*)d_in[4];
  const float* b = (const float*)d_in[5];
  float* out = (float*)d_out;
  const size_t lds_bytes = (size_t)LDS_DBL * sizeof(double);  // 160320
  altdiff_kernel<<<dim3(64), dim3(256), lds_bytes, stream>>>(Q, q, G, h, A, b, out);
}

// Round 12
// 656.845 us; speedup vs baseline: 1.0128x; 1.0128x over previous
//
#include <hip/hip_runtime.h>

#define NN 128
#define ME 32
#define DI 64
#define NZ 96
#define ROWD 130
#define MAXIT 5000

// ---- LDS layout (double offsets). R: [0, 16640). Total 20040 dbl = 160320 B <= 163840.
#define OFF_UN 16640
#define ROWB  (OFF_UN)           // [2][128] sweep row-k buffer (phase 2)
#define COLB  (OFF_UN + 256)     // [2][128] sweep col-k buffer (phase 2)
#define PLO2  (OFF_UN)           // [2][4][64] lo partials (loop)
#define PHI2  (OFF_UN + 512)     // [2][4][32] hi partials (loop)
#define TV0   (OFF_UN + 768)     // [2][64] obj per-lane terms (loop, pipelined)
#define TV1   (OFF_UN + 896)     // [2][16] obj stage-A sums (loop, pipelined)
#define FLG   (OFF_UN + 928)     // [2] convergence flag (loop, double 0/1)
#define YBUF  (OFF_UN)           // [128][12] Y block (stage 2)
#define KBUF  (OFF_UN + 1536)    // [12][96] K cols (stage 2)
#define CPART (OFF_UN + 1024)    // [2][128] (stage 3a)
#define VP    (OFF_UN + 1280)    // [4][128] (stage 3b)
#define BASEV (OFF_UN + 1792)    // [96] (persists through loop)
#define QBV   (OFF_UN + 1888)    // [96] (persists through loop)
#define FPART (OFF_UN + 1024)    // [2][128] (final)
#define RHSV  (OFF_UN + 1280)    // [128] (final)
#define XPART (OFF_UN + 1408)    // [2][128] (final)
#define CB    (OFF_UN + 2688)    // [128] c
#define QBUF  (OFF_UN + 2816)    // [128] q
#define V1    (OFF_UN + 2944)    // [128] Rc
#define V2    (OFF_UN + 3072)    // [128] Rq
#define HB    (OFF_UN + 3200)    // [64]
#define BB    (OFF_UN + 3264)    // [32]
#define CST   (OFF_UN + 3296)    // [8]: 0=u.c 1=q.u
#define ZBF   (OFF_UN + 3304)    // [96] z publish (final)
#define LDS_DBL (OFF_UN + 3400)  // 20040

// f32 SGPR broadcast. CONTRACT: source computed by all lanes of the wave.
__device__ __forceinline__ float rlf(float v, int lane) {
  return __uint_as_float((unsigned)__builtin_amdgcn_readlane((int)__float_as_uint(v), lane));
}

__global__ __launch_bounds__(256, 1) void altdiff_kernel(
    const float* __restrict__ Qg, const float* __restrict__ qg,
    const float* __restrict__ Gg, const float* __restrict__ hg,
    const float* __restrict__ Ag, const float* __restrict__ bg,
    float* __restrict__ out)
{
  extern __shared__ double ldsd[];
  double2* lds2 = (double2*)ldsd;

  const int bidx = blockIdx.x;
  const int tid  = threadIdx.x;
  const int w    = tid >> 6;     // wave 0..3
  const int l    = tid & 63;     // lane
  const int lm   = l & 31;
  const int ia   = tid & 127;    // 128-split index
  const int hh   = tid >> 7;     // 0..1 (wave-uniform)

  const float* Qb = Qg + (size_t)bidx * NN * NN;
  const float* Ab = Ag + (size_t)bidx * ME * NN;
  const float* Gb = Gg + (size_t)bidx * DI * NN;
  const float* qb = qg + (size_t)bidx * NN;
  const float* hb = hg + (size_t)bidx * DI;
  const float* bv = bg + (size_t)bidx * ME;

  // stage h, b, q (f64)
  if (tid < DI) ldsd[HB + tid] = (double)hb[tid];
  else if (tid < DI + ME) ldsd[BB + tid - DI] = (double)bv[tid - DI];
  if (tid >= 128) ldsd[QBUF + tid - 128] = (double)qb[tid - 128];

  const int r = tid >> 4, c = tid & 15;   // 8x8 register tile at rows 8r.., cols 8c..
  double acc[8][8];                       // ALL indices compile-time constant (no scratch)

  // ---------------- Phase 1: M = Q + A^T A + G^T G (f64) -> registers ----------------
  {
    const float4* Q4 = (const float4*)Qb;
#pragma unroll
    for (int rr = 0; rr < 8; ++rr) {
      float4 q0 = Q4[((8*r+rr) << 5) + 2*c];
      float4 q1 = Q4[((8*r+rr) << 5) + 2*c + 1];
      acc[rr][0]=(double)q0.x; acc[rr][1]=(double)q0.y; acc[rr][2]=(double)q0.z; acc[rr][3]=(double)q0.w;
      acc[rr][4]=(double)q1.x; acc[rr][5]=(double)q1.y; acc[rr][6]=(double)q1.z; acc[rr][7]=(double)q1.w;
    }
    const float4* A4 = (const float4*)Ab;
    for (int m = 0; m < ME; ++m) {
      float4 u0 = A4[(m << 5) + 2*r], u1 = A4[(m << 5) + 2*r + 1];
      float4 v0 = A4[(m << 5) + 2*c], v1 = A4[(m << 5) + 2*c + 1];
      double uu[8] = {(double)u0.x,(double)u0.y,(double)u0.z,(double)u0.w,
                      (double)u1.x,(double)u1.y,(double)u1.z,(double)u1.w};
      double vv[8] = {(double)v0.x,(double)v0.y,(double)v0.z,(double)v0.w,
                      (double)v1.x,(double)v1.y,(double)v1.z,(double)v1.w};
#pragma unroll
      for (int rr = 0; rr < 8; ++rr)
#pragma unroll
        for (int cc = 0; cc < 8; ++cc)
          acc[rr][cc] = fma(uu[rr], vv[cc], acc[rr][cc]);
    }
    const float4* G4 = (const float4*)Gb;
    for (int d = 0; d < DI; ++d) {
      float4 u0 = G4[(d << 5) + 2*r], u1 = G4[(d << 5) + 2*r + 1];
      float4 v0 = G4[(d << 5) + 2*c], v1 = G4[(d << 5) + 2*c + 1];
      double uu[8] = {(double)u0.x,(double)u0.y,(double)u0.z,(double)u0.w,
                      (double)u1.x,(double)u1.y,(double)u1.z,(double)u1.w};
      double vv[8] = {(double)v0.x,(double)v0.y,(double)v0.z,(double)v0.w,
                      (double)v1.x,(double)v1.y,(double)v1.z,(double)v1.w};
#pragma unroll
      for (int rr = 0; rr < 8; ++rr)
#pragma unroll
        for (int cc = 0; cc < 8; ++cc)
          acc[rr][cc] = fma(uu[rr], vv[cc], acc[rr][cc]);
    }
  }

  // ---------------- Phase 2: register-tile sweep, 1 barrier/pivot, double-buffered ----------
  {
    if (r == 0) {
#pragma unroll
      for (int cc = 0; cc < 8; ++cc) ldsd[ROWB + 8*c + cc] = acc[0][cc];
    }
    if (c == 0) {
#pragma unroll
      for (int rr = 0; rr < 8; ++rr) ldsd[COLB + 8*r + rr] = acc[rr][0];
    }
    __syncthreads();
    for (int k = 0; k < NN; ++k) {
      const int pb = (k & 1) << 7;
      const int krt = k >> 3, kcl = k & 7;
      double rowk[8], colv[8];
#pragma unroll
      for (int cc = 0; cc < 8; ++cc) rowk[cc] = ldsd[ROWB + pb + 8*c + cc];
#pragma unroll
      for (int rr = 0; rr < 8; ++rr) colv[rr] = ldsd[COLB + pb + 8*r + rr];
      const double dkk  = ldsd[ROWB + pb + k];     // same-address broadcast
      const double rcpd = 1.0 / dkk;               // pivots >= 1 (M >= I)
      double rdv[8];
#pragma unroll
      for (int cc = 0; cc < 8; ++cc) rdv[cc] = rowk[cc] * rcpd;
      const bool pivR = (r == krt), pivC = (c == krt);
#pragma unroll
      for (int rr = 0; rr < 8; ++rr) {
        const double cv = colv[rr] * rcpd;
        const bool pr = pivR && (rr == kcl);
#pragma unroll
        for (int cc = 0; cc < 8; ++cc) {
          double gen = fma(-cv, rowk[cc], acc[rr][cc]);
          acc[rr][cc] = pr ? rdv[cc] : gen;
        }
      }
      if (pivC) {
#pragma unroll
        for (int cc = 0; cc < 8; ++cc) if (cc == kcl) {
#pragma unroll
          for (int rr = 0; rr < 8; ++rr) {
            const bool pr2 = pivR && (rr == kcl);
            acc[rr][cc] = pr2 ? -rcpd : colv[rr] * rcpd;
          }
        }
      }
      if (k < NN - 1) {
        const int pb2 = ((k + 1) & 1) << 7;
        const int krt2 = (k + 1) >> 3, kcl2 = (k + 1) & 7;
        if (r == krt2) {
#pragma unroll
          for (int rr = 0; rr < 8; ++rr) if (rr == kcl2) {
#pragma unroll
            for (int cc = 0; cc < 8; ++cc) ldsd[ROWB + pb2 + 8*c + cc] = acc[rr][cc];
          }
        }
        if (c == krt2) {
#pragma unroll
          for (int cc = 0; cc < 8; ++cc) if (cc == kcl2) {
#pragma unroll
            for (int rr = 0; rr < 8; ++rr) ldsd[COLB + pb2 + 8*r + rr] = acc[rr][cc];
          }
        }
      }
      __syncthreads();
    }
#pragma unroll
    for (int rr = 0; rr < 8; ++rr) {
      double2* dst = (double2*)(ldsd + (8*r+rr)*ROWD + 8*c);
#pragma unroll
      for (int t = 0; t < 4; ++t) dst[t] = make_double2(acc[rr][2*t], acc[rr][2*t+1]);
    }
  }
  __syncthreads();

  // ---------------- Stage 2: K = B (R B^T) in 8 blocks of 12 cols (validated r6) --------
  float Kf[24], Kf2[24];
  for (int blk = 0; blk < 8; ++blk) {
    {
      const float* gp[6];
#pragma unroll
      for (int jj = 0; jj < 6; ++jj) {
        int it = 12*blk + 6*hh + jj;
        gp[jj] = (it < DI) ? (Gb + it*NN) : (Ab + (it - DI)*NN);
      }
      double a2[6] = {0,0,0,0,0,0};
#pragma unroll 4
      for (int t = 0; t < NN; ++t) {
        double rv = ldsd[t*ROWD + ia];
#pragma unroll
        for (int jj = 0; jj < 6; ++jj)
          a2[jj] = fma(rv, (double)gp[jj][t], a2[jj]);
      }
      double2* yst = (double2*)(ldsd + YBUF + ia*12 + 6*hh);
#pragma unroll
      for (int p = 0; p < 3; ++p) yst[p] = make_double2(a2[2*p], a2[2*p+1]);
    }
    __syncthreads();
    {
      const int r2 = (ia < NZ) ? ia : 0;
      const float* brow = (r2 < DI) ? (Gb + r2*NN) : (Ab + (r2 - DI)*NN);
      double a2[6] = {0,0,0,0,0,0};
#pragma unroll 4
      for (int t = 0; t < NN; ++t) {
        double bvv = (double)brow[t];
        const double2* yr = (const double2*)(ldsd + YBUF + t*12 + 6*hh);
        double2 y0 = yr[0], y1 = yr[1], y2 = yr[2];
        a2[0] = fma(bvv, y0.x, a2[0]); a2[1] = fma(bvv, y0.y, a2[1]);
        a2[2] = fma(bvv, y1.x, a2[2]); a2[3] = fma(bvv, y1.y, a2[3]);
        a2[4] = fma(bvv, y2.x, a2[4]); a2[5] = fma(bvv, y2.y, a2[5]);
      }
      if (ia < NZ) {
#pragma unroll
        for (int jj = 0; jj < 6; ++jj) ldsd[KBUF + (6*hh + jj)*NZ + ia] = a2[jj];
      }
    }
    __syncthreads();
    if (w == (blk >> 1)) {          // CONSTANT-index copies (r5 spill fix)
      if ((blk & 1) == 0) {
#pragma unroll
        for (int jj = 0; jj < 12; ++jj) {
          Kf [jj] = (float)ldsd[KBUF + jj*NZ + l];
          Kf2[jj] = (float)ldsd[KBUF + jj*NZ + 64 + lm];
        }
      } else {
#pragma unroll
        for (int jj = 0; jj < 12; ++jj) {
          Kf [12+jj] = (float)ldsd[KBUF + jj*NZ + l];
          Kf2[12+jj] = (float)ldsd[KBUF + jj*NZ + 64 + lm];
        }
      }
    }
    __syncthreads();
  }

  // ---------------- Stage 3a: c = q - G^T h - A^T b ----------------
  {
    double s = 0;
#pragma unroll 8
    for (int jc = 0; jc < 48; ++jc) {
      int j = 48*hh + jc;
      double coef = (j < DI) ? ldsd[HB + j] : ldsd[BB + j - DI];
      const float* src = (j < DI) ? (Gb + j*NN) : (Ab + (j - DI)*NN);
      s = fma(-(double)src[ia], coef, s);
    }
    ldsd[CPART + hh*128 + ia] = s;
  }
  __syncthreads();
  if (tid < NN) ldsd[CB + tid] = ldsd[QBUF + tid] + ldsd[CPART + tid] + ldsd[CPART + 128 + tid];
  __syncthreads();

  // ---------------- Stage 3b: v1 = R c, v2 = R q ----------------
  {
    double a = 0, b2 = 0;
#pragma unroll 4
    for (int tt = 0; tt < 64; ++tt) {
      int t = 64*hh + tt;
      double rv = ldsd[t*ROWD + ia];
      a  = fma(rv, ldsd[CB + t], a);
      b2 = fma(rv, ldsd[QBUF + t], b2);
    }
    ldsd[VP + hh*128 + ia] = a;
    ldsd[VP + 256 + hh*128 + ia] = b2;
  }
  __syncthreads();
  if (tid < NN) {
    ldsd[V1 + tid] = ldsd[VP + tid] + ldsd[VP + 128 + tid];
    ldsd[V2 + tid] = ldsd[VP + 256 + tid] + ldsd[VP + 384 + tid];
  }
  __syncthreads();

  // ---------------- Stage 3c: base = B v1, qB = B v2, scalars ----------------
  {
    const int r2 = (ia < NZ) ? ia : 0;
    const float* brow = (r2 < DI) ? (Gb + r2*NN) : (Ab + (r2 - DI)*NN);
    const int voff = hh ? V2 : V1;
    double s = 0;
#pragma unroll 4
    for (int t = 0; t < NN; ++t) s = fma((double)brow[t], ldsd[voff + t], s);
    if (ia < NZ) ldsd[(hh ? QBV : BASEV) + ia] = s;
  }
  if (w == 0) {
    double pc = ldsd[V1+l]*ldsd[CB+l]   + ldsd[V1+64+l]*ldsd[CB+64+l];
    double pq = ldsd[V1+l]*ldsd[QBUF+l] + ldsd[V1+64+l]*ldsd[QBUF+64+l];
#pragma unroll
    for (int off = 32; off >= 1; off >>= 1) { pc += __shfl_xor(pc, off); pq += __shfl_xor(pq, off); }
    if (l == 0) { ldsd[CST] = pc; ldsd[CST+1] = pq; }
  }
  __syncthreads();

  // ---------------- Loop setup: BALANCED per-wave roles ----------------
  // w0: ylo/nu/zlo + base seed          | w1: ylo/nu/zlo + stage B + flag (obj recurrence)
  // w2: all partials + tv + z-ring      | w3: yhi/lam/zhi + stage A
  const double h_r   = ldsd[HB + l];
  const double b_r   = ldsd[BB + lm];
  const double baseA = ldsd[BASEV + l];
  const double baseB = ldsd[BASEV + 64 + lm];
  const double qvA   = ldsd[QBV + l];
  const double qvB   = ldsd[QBV + 64 + lm];
  const double S_uc  = ldsd[CST], S_qu = ldsd[CST + 1];
  double nu = 0.0, lam = 0.0;
  double zlo = 0.0, zhi = 0.0;
  double zAlo = 0.0, zAhi = 0.0, zBlo = 0.0, zBhi = 0.0, zClo = 0.0, zChi = 0.0;  // wave-2 ring
  double res_prev = 1000.0, res_cur = -100.0;   // wave-1 obj recurrence

  // prologue: partials for body 0 (z = 0 -> seed only), buffer 0; flag init
  {
    double a0 = (w == 0) ? baseA : 0.0;
    double a1 = (w == 0) ? baseB : 0.0;
    ldsd[PLO2 + w*64 + l] = a0;
    if (l < 32) ldsd[PHI2 + w*32 + l] = a1;
    if (tid == 0) { ldsd[FLG] = 0.0; ldsd[FLG + 1] = 0.0; }
  }

  // ---------------- ADMM loop: 1 barrier/body; obj pipeline spread over slack waves ----
  for (int it = 0; it < MAXIT + 3; ++it) {
    __syncthreads();
    const int p  = (it & 1) << 8;
    const int ph = (it & 1) << 7;
    const int bprev = (it + 1) & 1;       // (it-1)&1
    // flag (stored body it-1 by wave 1, decision for obj_{it-3}) — broadcast b64
    double fl = ldsd[FLG + bprev];
    // stage B loads (wave 1, pipeline it-2): wave-uniform broadcast
    double t1v[16];
    if (w == 1) {
      const double2* tp = (const double2*)(ldsd + TV1 + bprev*16);
#pragma unroll
      for (int u = 0; u < 8; ++u) { double2 v = tp[u]; t1v[2*u] = v.x; t1v[2*u+1] = v.y; }
    }
    // stage A loads (wave 3, pipeline it-1)
    double a40 = 0, a41 = 0, a42 = 0, a43 = 0;
    if (w == 3) {
      const double2* t0p = (const double2*)(ldsd + TV0 + bprev*64 + (l & 15)*4);
      double2 v0 = t0p[0], v1 = t0p[1];
      a40 = v0.x; a41 = v0.y; a42 = v1.x; a43 = v1.y;
    }
    // partial reads — pruned per wave
    double ylo = 0.0, yhi = 0.0;
    if (w != 3)
      ylo = (ldsd[PLO2 + p + l]       + ldsd[PLO2 + p + 64 + l])
          + (ldsd[PLO2 + p + 128 + l] + ldsd[PLO2 + p + 192 + l]);
    if (w >= 2)
      yhi = (ldsd[PHI2 + ph + lm]      + ldsd[PHI2 + ph + 32 + lm])
          + (ldsd[PHI2 + ph + 64 + lm] + ldsd[PHI2 + ph + 96 + lm]);
    // uniform deferred break BEFORE ring shift: ring = top(it-2) in zC (= stopping body t*)
    if (it >= 3 && fl != 0.0) break;
    // z ring shift (wave 2 only; zA = z at top of THIS body)
    if (w == 2) { zClo = zBlo; zChi = zBhi; zBlo = zAlo; zBhi = zAhi; zAlo = zlo; zAhi = zhi; }
    if (it < MAXIT) {
      if (w != 3) {                 // nu/zlo update (waves 0,1,2)
        double sk = fmax(0.0, -nu - ylo + h_r);
        nu  = nu + ylo + sk - h_r;
        zlo = nu + sk;
      }
      if (w >= 2) {                 // lam/zhi update (waves 2,3)
        lam = lam + yhi - b_r;
        zhi = lam;
      }
      // f32 matvec for next body (f32 K regs, f32 broadcast; base added in f64 on wave 0)
      const float zflo = (float)zlo;
      const float zfhi = (float)zhi;
      float a0f = 0.f, a0g = 0.f, a1f = 0.f, a1g = 0.f;
      if (w == 0) {
#pragma unroll
        for (int j = 0; j < 24; j += 2) {
          float zj  = rlf(zflo, j);
          float zj1 = rlf(zflo, j + 1);
          a0f = fmaf(Kf[j],   zj,  a0f); a1f = fmaf(Kf2[j],   zj,  a1f);
          a0g = fmaf(Kf[j+1], zj1, a0g); a1g = fmaf(Kf2[j+1], zj1, a1g);
        }
      } else if (w == 1) {
#pragma unroll
        for (int j = 0; j < 24; j += 2) {
          float zj  = rlf(zflo, 24 + j);
          float zj1 = rlf(zflo, 24 + j + 1);
          a0f = fmaf(Kf[j],   zj,  a0f); a1f = fmaf(Kf2[j],   zj,  a1f);
          a0g = fmaf(Kf[j+1], zj1, a0g); a1g = fmaf(Kf2[j+1], zj1, a1g);
        }
      } else if (w == 2) {
#pragma unroll
        for (int j = 0; j < 16; j += 2) {
          float zj  = rlf(zflo, 48 + j);
          float zj1 = rlf(zflo, 48 + j + 1);
          a0f = fmaf(Kf[j],   zj,  a0f); a1f = fmaf(Kf2[j],   zj,  a1f);
          a0g = fmaf(Kf[j+1], zj1, a0g); a1g = fmaf(Kf2[j+1], zj1, a1g);
        }
#pragma unroll
        for (int j = 0; j < 8; j += 2) {
          float zj  = rlf(zfhi, j);
          float zj1 = rlf(zfhi, j + 1);
          a0f = fmaf(Kf[16+j],   zj,  a0f); a1f = fmaf(Kf2[16+j],   zj,  a1f);
          a0g = fmaf(Kf[16+j+1], zj1, a0g); a1g = fmaf(Kf2[16+j+1], zj1, a1g);
        }
      } else {
#pragma unroll
        for (int j = 0; j < 24; j += 2) {
          float zj  = rlf(zfhi, 8 + j);
          float zj1 = rlf(zfhi, 8 + j + 1);
          a0f = fmaf(Kf[j],   zj,  a0f); a1f = fmaf(Kf2[j],   zj,  a1f);
          a0g = fmaf(Kf[j+1], zj1, a0g); a1g = fmaf(Kf2[j+1], zj1, a1g);
        }
      }
      double pa0 = (double)(a0f + a0g);
      double pa1 = (double)(a1f + a1g);
      if (w == 0) { pa0 += baseA; pa1 += baseB; }
      ldsd[PLO2 + (p ^ 256) + w*64 + l] = pa0;
      if (l < 32) ldsd[PHI2 + (ph ^ 128) + w*32 + l] = pa1;
      // tv for pipeline `it` (wave 2 — it holds ylo, yhi, and the ring)
      if (w == 2) {
        double tv = fma(qvA, zAlo, -0.5*(zAlo*(baseA + ylo) + ylo*ylo));
        tv += (l < 32) ? fma(qvB, zAhi, -0.5*(zAhi*(baseB + yhi) + yhi*yhi)) : 0.0;
        ldsd[TV0 + (it & 1)*64 + l] = tv;
      }
    }
    // stage A store (wave 3, pipeline it-1): valid when body it-1 wrote TV0
    if (w == 3 && l < 16 && it >= 1 && it <= MAXIT)
      ldsd[TV1 + (it & 1)*16 + l] = (a40 + a41) + (a42 + a43);
    // stage B (wave 1): obj_{it-2} -> rel -> flag
    if (w == 1 && it >= 2 && it <= MAXIT + 1) {
      double s1 = ((t1v[0] + t1v[1]) + (t1v[2] + t1v[3])) + ((t1v[4] + t1v[5]) + (t1v[6] + t1v[7]));
      double s2 = ((t1v[8] + t1v[9]) + (t1v[10] + t1v[11])) + ((t1v[12] + t1v[13]) + (t1v[14] + t1v[15]));
      double obj = (s1 + s2) - 0.5*S_uc + S_qu;
      res_prev = res_cur; res_cur = obj;
      if (l == 0)
        ldsd[FLG + (it & 1)] = (fabs((res_cur - res_prev) / res_prev) <= 1e-5) ? 1.0 : 0.0;
    }
  }

  // ---------------- Final: publish z (wave 2 ring: zC = top-of-stopping-body) -> LDS ------
  if (w == 2) {
    ldsd[ZBF + l] = zClo;
    if (l < 32) ldsd[ZBF + 64 + l] = zChi;
  }
  __syncthreads();
  // x = R (c + B^T z); z read via broadcast LDS loads
  {
    double s = 0;
#pragma unroll 8
    for (int jc = 0; jc < 48; ++jc) {
      int j = 48*hh + jc;
      double zj = ldsd[ZBF + j];
      const float* src = (j < DI) ? (Gb + j*NN) : (Ab + (j - DI)*NN);
      s = fma((double)src[ia], zj, s);
    }
    ldsd[FPART + hh*128 + ia] = s;
  }
  __syncthreads();
  if (tid < NN) ldsd[RHSV + tid] = ldsd[CB + tid] + ldsd[FPART + tid] + ldsd[FPART + 128 + tid];
  __syncthreads();
  {
    double s = 0;
#pragma unroll 4
    for (int tt = 0; tt < 64; ++tt) {
      int t = 64*hh + tt;
      s = fma(ldsd[t*ROWD + ia], ldsd[RHSV + t], s);   // R[t][ia] = R[ia][t]
    }
    ldsd[XPART + hh*128 + ia] = s;
  }
  __syncthreads();
  if (tid < NN)
    out[(size_t)bidx * NN + tid] = (float)(ldsd[XPART + tid] + ldsd[XPART + 128 + tid]);
}

extern "C" void kernel_launch(void* const* d_in, const int* in_sizes, int n_in,
                              void* d_out, int out_size, void* d_ws, size_t ws_size,
                              hipStream_t stream) {
  (void)in_sizes; (void)n_in; (void)out_size; (void)d_ws; (void)ws_size;
  const float* Q = (const float*)d_in[0];
  const float* q = (const float*)d_in[1];
  const float* G = (const float*)d_in[2];
  const float* h = (const float*)d_in[3];
  const float* A = (const float*)d_in[4];
  const float* b = (const float*)d_in[5];
  float* out = (float*)d_out;
  const size_t lds_bytes = (size_t)LDS_DBL * sizeof(double);  // 160320
  altdiff_kernel<<<dim3(64), dim3(256), lds_bytes, stream>>>(Q, q, G, h, A, b, out);
}